// Round 1
// baseline (4303.698 us; speedup 1.0000x reference)
//
#include <hip/hip_runtime.h>
#include <cstdint>
#include <cstddef>

#define N_NODES 2048
#define N_PTS 256
#define N_EDGE 32768
#define N_EDGE_TOT (N_EDGE + N_NODES)  // 34816, with self-loops appended
#define NPG 32                          // nodes per graph (2048/64)

// ---------- helpers ----------
__device__ inline unsigned fenc(float x) {
  unsigned u = __float_as_uint(x);
  return (u & 0x80000000u) ? ~u : (u | 0x80000000u);
}
__device__ inline float fdec(unsigned u) {
  return __uint_as_float((u & 0x80000000u) ? (u ^ 0x80000000u) : ~u);
}
__device__ inline int e_src(const int* ei, int e) { return e < N_EDGE ? ei[e] : e - N_EDGE; }
__device__ inline int e_dst(const int* ei, int e) { return e < N_EDGE ? ei[N_EDGE + e] : e - N_EDGE; }

// ---------- graph build: CSR of in-edges grouped by dst ----------
__global__ void k_hist(const int* __restrict__ ei, int* __restrict__ cnt) {
  int e = blockIdx.x * 256 + threadIdx.x;
  if (e >= N_EDGE_TOT) return;
  atomicAdd(&cnt[e_dst(ei, e)], 1);
}

__global__ __launch_bounds__(256) void k_scan(const int* __restrict__ cnt, int* __restrict__ row_ptr) {
  __shared__ int sS[256];
  const int t = threadIdx.x;
  int v[8]; int s = 0;
#pragma unroll
  for (int i = 0; i < 8; i++) { v[i] = cnt[t * 8 + i]; s += v[i]; }
  sS[t] = s;
  __syncthreads();
  for (int off = 1; off < 256; off <<= 1) {
    int x = 0;
    if (t >= off) x = sS[t - off];
    __syncthreads();
    sS[t] += x;
    __syncthreads();
  }
  int run = sS[t] - s;  // exclusive prefix
#pragma unroll
  for (int i = 0; i < 8; i++) { row_ptr[t * 8 + i] = run; run += v[i]; }
  if (t == 255) row_ptr[2048] = run;
}

__global__ void k_scatter(const int* __restrict__ ei, const int* __restrict__ row_ptr,
                          int* __restrict__ cur, int* __restrict__ edge_list) {
  int e = blockIdx.x * 256 + threadIdx.x;
  if (e >= N_EDGE_TOT) return;
  int d = e_dst(ei, e);
  int pos = row_ptr[d] + atomicAdd(&cur[d], 1);
  edge_list[pos] = e;
}

// ---------- PointNet fused (layers 1-5 + max-pool) ----------
// 512 threads/block, one block per node. Layers 2-4 are LDS tile-GEMMs over
// 64-point chunks; layer 5 holds one w5 column in 128 VGPRs per thread
// (feature-per-thread) and reads h4 rows via broadcast ds_read_b128.
template <int CW>
__device__ inline void node_layer(const float* __restrict__ in, const int is,
                                  const float* __restrict__ w, const int wst,
                                  float* __restrict__ out, const int os, const int t) {
  const int r0 = (t >> 4) * 2;
  const int c0 = (t & 15) * CW;
  float acc[2][CW];
#pragma unroll
  for (int i = 0; i < 2; i++)
#pragma unroll
    for (int j = 0; j < CW; j++) acc[i][j] = 0.0f;

  for (int k = 0; k < 64; k++) {
    float av0 = in[r0 * is + k];
    float av1 = in[(r0 + 1) * is + k];
    const float* wr = w + k * wst + c0;
    float4 w0 = *(const float4*)wr;
    acc[0][0] = fmaf(av0, w0.x, acc[0][0]); acc[1][0] = fmaf(av1, w0.x, acc[1][0]);
    acc[0][1] = fmaf(av0, w0.y, acc[0][1]); acc[1][1] = fmaf(av1, w0.y, acc[1][1]);
    acc[0][2] = fmaf(av0, w0.z, acc[0][2]); acc[1][2] = fmaf(av1, w0.z, acc[1][2]);
    acc[0][3] = fmaf(av0, w0.w, acc[0][3]); acc[1][3] = fmaf(av1, w0.w, acc[1][3]);
    if constexpr (CW == 8) {
      float4 w1v = *(const float4*)(wr + 4);
      acc[0][4] = fmaf(av0, w1v.x, acc[0][4]); acc[1][4] = fmaf(av1, w1v.x, acc[1][4]);
      acc[0][5] = fmaf(av0, w1v.y, acc[0][5]); acc[1][5] = fmaf(av1, w1v.y, acc[1][5]);
      acc[0][6] = fmaf(av0, w1v.z, acc[0][6]); acc[1][6] = fmaf(av1, w1v.z, acc[1][6]);
      acc[0][7] = fmaf(av0, w1v.w, acc[0][7]); acc[1][7] = fmaf(av1, w1v.w, acc[1][7]);
    }
  }
#pragma unroll
  for (int i = 0; i < 2; i++)
#pragma unroll
    for (int j = 0; j < CW; j++)
      out[(r0 + i) * os + c0 + j] = fmaxf(acc[i][j], 0.0f);
}

__global__ __launch_bounds__(512, 2) void k_pointnet(
    const float* __restrict__ pcd,
    const float* __restrict__ w1, const float* __restrict__ w2,
    const float* __restrict__ w3, const float* __restrict__ w4,
    const float* __restrict__ w5, float* __restrict__ xcat) {
  __shared__ float sW1[3][64];
  __shared__ float sW2[64][64];
  __shared__ float sW3[64][64];
  __shared__ float sW4[64][128];
  __shared__ float sP[64][4];
  __shared__ float sA[64][68];   // +4 pad: conflict-free strided row reads
  __shared__ float sB[64][68];
  __shared__ float sC[64][132];  // h4 chunk
  const int t = threadIdx.x;
  const int node = blockIdx.x;

  for (int i = t; i < 3 * 64; i += 512) sW1[i >> 6][i & 63] = w1[i];
  for (int i = t; i < 64 * 64; i += 512) sW2[i >> 6][i & 63] = w2[i];
  for (int i = t; i < 64 * 64; i += 512) sW3[i >> 6][i & 63] = w3[i];
  for (int i = t; i < 64 * 128; i += 512) sW4[i >> 7][i & 127] = w4[i];

  // one w5 column (feature f = t) in registers; static indexing via full unroll
  float w5r[128];
#pragma unroll
  for (int k = 0; k < 128; k++) w5r[k] = w5[k * 512 + t];

  float best = 0.0f;  // layer-5 relu => max >= 0

  for (int c = 0; c < 4; c++) {
    __syncthreads();  // previous chunk's phase-B reads done
    const float* pc = pcd + ((size_t)node * N_PTS + c * 64) * 3;
    for (int i = t; i < 64 * 3; i += 512) sP[i / 3][i % 3] = pc[i];
    __syncthreads();
    {  // layer 1: 3 -> 64
      int j = t & 63, pg = t >> 6;
#pragma unroll
      for (int i = 0; i < 8; i++) {
        int p = pg * 8 + i;
        float v = sP[p][0] * sW1[0][j] + sP[p][1] * sW1[1][j] + sP[p][2] * sW1[2][j];
        sA[p][j] = fmaxf(v, 0.0f);
      }
    }
    __syncthreads();
    node_layer<4>(&sA[0][0], 68, &sW2[0][0], 64, &sB[0][0], 68, t);   // 64->64
    __syncthreads();
    node_layer<4>(&sB[0][0], 68, &sW3[0][0], 64, &sA[0][0], 68, t);   // 64->64
    __syncthreads();
    node_layer<8>(&sA[0][0], 68, &sW4[0][0], 128, &sC[0][0], 132, t); // 64->128
    __syncthreads();
    // layer 5 + relu + running max: dot(sC[p][:], w5r)
    for (int p = 0; p < 64; p++) {
      const float4* row = (const float4*)&sC[p][0];
      float acc = 0.0f;
#pragma unroll
      for (int k4 = 0; k4 < 32; k4++) {
        float4 a = row[k4];
        acc = fmaf(a.x, w5r[4 * k4 + 0], acc);
        acc = fmaf(a.y, w5r[4 * k4 + 1], acc);
        acc = fmaf(a.z, w5r[4 * k4 + 2], acc);
        acc = fmaf(a.w, w5r[4 * k4 + 3], acc);
      }
      best = fmaxf(best, acc);
    }
  }
  // write into LEFT half of the concat buffer [N, 1024]
  xcat[(size_t)node * 1024 + t] = best;
}

// ---------- multi-feature MLP part 1 (vd @ mf_w1 + b1, relu) into RIGHT half ----------
__global__ void k_vdf(const float* __restrict__ vol, const float* __restrict__ dist,
                      const float* __restrict__ ec, const float* __restrict__ w1,
                      const float* __restrict__ b1, float* __restrict__ xcat) {
  int idx = blockIdx.x * 256 + threadIdx.x;  // 2048*512
  int n = idx >> 9, j = idx & 511;
  float v = vol[n] * w1[j] + dist[n] * w1[512 + j] + ec[n] * w1[1024 + j] + b1[j];
  xcat[(size_t)n * 1024 + 512 + j] = fmaxf(v, 0.0f);
}

// ---------- generic f32 GEMM: C = act(A[M,K] @ W[K,N] + bias), tiles 64x64x16 ----------
template <int ACT>
__global__ __launch_bounds__(256) void k_gemm(const float* __restrict__ A,
                                              const float* __restrict__ W,
                                              const float* __restrict__ bias,
                                              float* __restrict__ C, int M, int N, int K) {
  __shared__ float sA[64][17];
  __shared__ float sW[16][64];
  const int t = threadIdx.x;
  const int row0 = blockIdx.x * 64, col0 = blockIdx.y * 64;
  const int tr = t >> 4, tc = t & 15;
  const int la_r = t >> 2, la_c = (t & 3) * 4;
  const int lw_r = t >> 4, lw_c = (t & 15) * 4;
  float acc[4][4] = {};
  for (int kb = 0; kb < K; kb += 16) {
    __syncthreads();
    float4 av = *(const float4*)(A + (size_t)(row0 + la_r) * K + kb + la_c);
    sA[la_r][la_c + 0] = av.x; sA[la_r][la_c + 1] = av.y;
    sA[la_r][la_c + 2] = av.z; sA[la_r][la_c + 3] = av.w;
    float4 wv = *(const float4*)(W + (size_t)(kb + lw_r) * N + col0 + lw_c);
    *(float4*)&sW[lw_r][lw_c] = wv;
    __syncthreads();
#pragma unroll
    for (int kk = 0; kk < 16; kk++) {
      float a0 = sA[tr * 4 + 0][kk], a1 = sA[tr * 4 + 1][kk];
      float a2 = sA[tr * 4 + 2][kk], a3 = sA[tr * 4 + 3][kk];
      float4 w4 = *(const float4*)&sW[kk][tc * 4];
      acc[0][0] = fmaf(a0, w4.x, acc[0][0]); acc[0][1] = fmaf(a0, w4.y, acc[0][1]);
      acc[0][2] = fmaf(a0, w4.z, acc[0][2]); acc[0][3] = fmaf(a0, w4.w, acc[0][3]);
      acc[1][0] = fmaf(a1, w4.x, acc[1][0]); acc[1][1] = fmaf(a1, w4.y, acc[1][1]);
      acc[1][2] = fmaf(a1, w4.z, acc[1][2]); acc[1][3] = fmaf(a1, w4.w, acc[1][3]);
      acc[2][0] = fmaf(a2, w4.x, acc[2][0]); acc[2][1] = fmaf(a2, w4.y, acc[2][1]);
      acc[2][2] = fmaf(a2, w4.z, acc[2][2]); acc[2][3] = fmaf(a2, w4.w, acc[2][3]);
      acc[3][0] = fmaf(a3, w4.x, acc[3][0]); acc[3][1] = fmaf(a3, w4.y, acc[3][1]);
      acc[3][2] = fmaf(a3, w4.z, acc[3][2]); acc[3][3] = fmaf(a3, w4.w, acc[3][3]);
    }
  }
#pragma unroll
  for (int i = 0; i < 4; i++) {
    int r = row0 + tr * 4 + i;
#pragma unroll
    for (int j = 0; j < 4; j++) {
      int c = col0 + tc * 4 + j;
      float v = acc[i][j] + bias[c];
      if (ACT == 1) v = fmaxf(v, 0.0f);
      C[(size_t)r * N + c] = v;
    }
  }
}

// ---------- GATv2 edge scores + segment max (one wave per edge) ----------
__global__ void k_edge_score(const float* __restrict__ xl, const float* __restrict__ xr,
                             const float* __restrict__ att, const int* __restrict__ ei,
                             float* __restrict__ score, unsigned* __restrict__ m_enc) {
  __shared__ float sAtt[512];
  const int t = threadIdx.x;
  for (int i = t; i < 512; i += 256) sAtt[i] = att[i];
  __syncthreads();
  const int wv = t >> 6, l = t & 63;
  const int e = blockIdx.x * 4 + wv;
  if (e >= N_EDGE_TOT) return;
  const int s = e_src(ei, e), d = e_dst(ei, e);
  const float* xls = xl + (size_t)s * 512;
  const float* xrd = xr + (size_t)d * 512;
  float ps[8];
#pragma unroll
  for (int h = 0; h < 8; h++) {
    float v = xls[h * 64 + l] + xrd[h * 64 + l];
    v = v > 0.0f ? v : 0.2f * v;  // leaky_relu(0.2)
    ps[h] = v * sAtt[h * 64 + l];
  }
#pragma unroll
  for (int off = 1; off < 64; off <<= 1)
#pragma unroll
    for (int h = 0; h < 8; h++) ps[h] += __shfl_xor(ps[h], off);
  if (l == 0) {
    size_t base = (size_t)e * 8;
#pragma unroll
    for (int h = 0; h < 8; h++) {
      score[base + h] = ps[h];
      atomicMax(&m_enc[d * 8 + h], fenc(ps[h]));
    }
  }
}

// ---------- p = exp(score - m[dst]); denom = segment_sum ----------
__global__ void k_edge_p(const float* __restrict__ score, const unsigned* __restrict__ m_enc,
                         const int* __restrict__ ei, float* __restrict__ p,
                         float* __restrict__ denom) {
  int idx = blockIdx.x * 256 + threadIdx.x;
  if (idx >= N_EDGE_TOT * 8) return;
  int e = idx >> 3, h = idx & 7;
  int d = e_dst(ei, e);
  float m = fdec(m_enc[d * 8 + h]);
  float pv = expf(score[idx] - m);
  p[idx] = pv;
  atomicAdd(&denom[d * 8 + h], pv);
}

// ---------- out[n] = sum_e alpha * xl[src] + bias (CSR, no atomics) ----------
template <int ACT>
__global__ __launch_bounds__(256) void k_aggregate(
    const float* __restrict__ xl, const float* __restrict__ p, const float* __restrict__ denom,
    const int* __restrict__ row_ptr, const int* __restrict__ edge_list,
    const int* __restrict__ ei, const float* __restrict__ bias, float* __restrict__ out) {
  __shared__ float sInv[8];
  const int n = blockIdx.x, t = threadIdx.x;
  if (t < 8) sInv[t] = 1.0f / denom[n * 8 + t];
  __syncthreads();
  const int f0 = t, f1 = t + 256;
  const int h0 = f0 >> 6, h1 = f1 >> 6;
  float acc0 = 0.0f, acc1 = 0.0f;
  const int beg = row_ptr[n], end = row_ptr[n + 1];
  for (int i = beg; i < end; i++) {
    const int e = edge_list[i];
    const int s = e_src(ei, e);
    const float* xs = xl + (size_t)s * 512;
    const float a0 = p[(size_t)e * 8 + h0] * sInv[h0];
    const float a1 = p[(size_t)e * 8 + h1] * sInv[h1];
    acc0 = fmaf(a0, xs[f0], acc0);
    acc1 = fmaf(a1, xs[f1], acc1);
  }
  float v0 = acc0 + bias[f0], v1 = acc1 + bias[f1];
  if (ACT == 1) { v0 = fmaxf(v0, 0.0f); v1 = fmaxf(v1, 0.0f); }
  out[(size_t)n * 512 + f0] = v0;
  out[(size_t)n * 512 + f1] = v1;
}

// ---------- logits + BCE loss + per-graph argmax hits ----------
__global__ __launch_bounds__(1024) void k_final(const float* __restrict__ hc2,
                                                const float* __restrict__ w3,
                                                const float* __restrict__ b3,
                                                const float* __restrict__ y,
                                                float* __restrict__ out) {
  __shared__ float sL[2048];
  __shared__ float sRed[1024];
  __shared__ float sW[64];
  const int t = threadIdx.x;
  if (t < 64) sW[t] = w3[t];
  __syncthreads();
  float lp = 0.0f;
  for (int n = t; n < 2048; n += 1024) {
    const float4* r = (const float4*)(hc2 + (size_t)n * 64);
    float a = 0.0f;
#pragma unroll
    for (int k = 0; k < 16; k++) {
      float4 v = r[k];
      a += v.x * sW[4 * k] + v.y * sW[4 * k + 1] + v.z * sW[4 * k + 2] + v.w * sW[4 * k + 3];
    }
    a += b3[0];
    sL[n] = a;
    lp += fmaxf(a, 0.0f) - a * y[n] + log1pf(expf(-fabsf(a)));
  }
  sRed[t] = lp;
  __syncthreads();
  for (int off = 512; off > 0; off >>= 1) {
    if (t < off) sRed[t] += sRed[t + off];
    __syncthreads();
  }
  if (t == 0) out[0] = sRed[0] * (1.0f / 2048.0f);
  __syncthreads();
  float hit = 0.0f;
  if (t < 64) {
    const int base = t * NPG;
    float bl = sL[base]; int bi = 0;
    float by = y[base];  int byi = 0;
    for (int i = 1; i < NPG - 1; i++) {  // [:, :-1] -> 31 entries, first-max tie rule
      float v = sL[base + i];
      if (v > bl) { bl = v; bi = i; }
      float w = y[base + i];
      if (w > by) { by = w; byi = i; }
    }
    hit = (bi == byi) ? 1.0f : 0.0f;
  }
  __syncthreads();
  sRed[t] = hit;
  __syncthreads();
  for (int off = 512; off > 0; off >>= 1) {
    if (t < off) sRed[t] += sRed[t + off];
    __syncthreads();
  }
  if (t == 0) out[1] = sRed[0] * (1.0f / 64.0f);
}

// ---------- workspace layout (float units) ----------
constexpr size_t OFF_XCAT = 0;                                  // [2048,1024]
constexpr size_t OFF_X1   = OFF_XCAT + (size_t)2048 * 1024;     // [2048,512]
constexpr size_t OFF_XL   = OFF_X1 + (size_t)2048 * 512;
constexpr size_t OFF_XR   = OFF_XL + (size_t)2048 * 512;
constexpr size_t OFF_G1   = OFF_XR + (size_t)2048 * 512;
constexpr size_t OFF_G2   = OFF_G1 + (size_t)2048 * 512;
constexpr size_t OFF_HC1  = OFF_G2 + (size_t)2048 * 512;        // [2048,64]
constexpr size_t OFF_HC2  = OFF_HC1 + (size_t)2048 * 64;
constexpr size_t OFF_SC   = OFF_HC2 + (size_t)2048 * 64;        // [34816,8]
constexpr size_t OFF_P    = OFF_SC + (size_t)N_EDGE_TOT * 8;
constexpr size_t OFF_M    = OFF_P + (size_t)N_EDGE_TOT * 8;     // u32 [2048,8]
constexpr size_t OFF_DEN  = OFF_M + (size_t)2048 * 8;
constexpr size_t OFF_RP   = OFF_DEN + (size_t)2048 * 8;         // int [2052]
constexpr size_t OFF_CNT  = OFF_RP + 2052;                      // int [2048]
constexpr size_t OFF_EL   = OFF_CNT + 2048;                     // int [34816]

extern "C" void kernel_launch(void* const* d_in, const int* in_sizes, int n_in,
                              void* d_out, int out_size, void* d_ws, size_t ws_size,
                              hipStream_t stream) {
  const float* pcd   = (const float*)d_in[0];
  const float* vol   = (const float*)d_in[1];
  const float* dist  = (const float*)d_in[2];
  const float* ecnt  = (const float*)d_in[3];
  const float* y     = (const float*)d_in[4];
  const float* pn_w1 = (const float*)d_in[5];
  const float* pn_w2 = (const float*)d_in[6];
  const float* pn_w3 = (const float*)d_in[7];
  const float* pn_w4 = (const float*)d_in[8];
  const float* pn_w5 = (const float*)d_in[9];
  const float* mf_w1 = (const float*)d_in[10];
  const float* mf_b1 = (const float*)d_in[11];
  const float* mf_w2 = (const float*)d_in[12];
  const float* mf_b2 = (const float*)d_in[13];
  const float* g1_wl = (const float*)d_in[14];
  const float* g1_bl = (const float*)d_in[15];
  const float* g1_wr = (const float*)d_in[16];
  const float* g1_br = (const float*)d_in[17];
  const float* g1_at = (const float*)d_in[18];
  const float* g1_bi = (const float*)d_in[19];
  const float* g2_wl = (const float*)d_in[20];
  const float* g2_bl = (const float*)d_in[21];
  const float* g2_wr = (const float*)d_in[22];
  const float* g2_br = (const float*)d_in[23];
  const float* g2_at = (const float*)d_in[24];
  const float* g2_bi = (const float*)d_in[25];
  const float* cl_w1 = (const float*)d_in[26];
  const float* cl_b1 = (const float*)d_in[27];
  const float* cl_w2 = (const float*)d_in[28];
  const float* cl_b2 = (const float*)d_in[29];
  const float* cl_w3 = (const float*)d_in[30];
  const float* cl_b3 = (const float*)d_in[31];
  const int*   ei    = (const int*)d_in[32];
  float* out = (float*)d_out;
  float* ws  = (float*)d_ws;

  float* xcat = ws + OFF_XCAT;
  float* x1   = ws + OFF_X1;
  float* xlb  = ws + OFF_XL;
  float* xrb  = ws + OFF_XR;
  float* g1o  = ws + OFF_G1;
  float* g2o  = ws + OFF_G2;
  float* hc1  = ws + OFF_HC1;
  float* hc2  = ws + OFF_HC2;
  float* sc   = ws + OFF_SC;
  float* pbuf = ws + OFF_P;
  unsigned* menc = (unsigned*)(ws + OFF_M);
  float* den  = ws + OFF_DEN;
  int* rp     = (int*)(ws + OFF_RP);
  int* cnt    = (int*)(ws + OFF_CNT);
  int* el     = (int*)(ws + OFF_EL);

  // --- build CSR by dst (shared by both GAT layers) ---
  hipMemsetAsync(cnt, 0, 2048 * sizeof(int), stream);
  k_hist<<<N_EDGE_TOT / 256, 256, 0, stream>>>(ei, cnt);
  k_scan<<<1, 256, 0, stream>>>(cnt, rp);
  hipMemsetAsync(cnt, 0, 2048 * sizeof(int), stream);
  k_scatter<<<N_EDGE_TOT / 256, 256, 0, stream>>>(ei, rp, cnt, el);

  // --- PointNet + multi-feature ---
  k_pointnet<<<N_NODES, 512, 0, stream>>>(pcd, pn_w1, pn_w2, pn_w3, pn_w4, pn_w5, xcat);
  k_vdf<<<2048 * 512 / 256, 256, 0, stream>>>(vol, dist, ecnt, mf_w1, mf_b1, xcat);
  k_gemm<1><<<dim3(32, 8), 256, 0, stream>>>(xcat, mf_w2, mf_b2, x1, 2048, 512, 1024);

  // --- GAT layer 1 ---
  k_gemm<0><<<dim3(32, 8), 256, 0, stream>>>(x1, g1_wl, g1_bl, xlb, 2048, 512, 512);
  k_gemm<0><<<dim3(32, 8), 256, 0, stream>>>(x1, g1_wr, g1_br, xrb, 2048, 512, 512);
  hipMemsetAsync(menc, 0, 2048 * 8 * sizeof(unsigned), stream);
  hipMemsetAsync(den, 0, 2048 * 8 * sizeof(float), stream);
  k_edge_score<<<N_EDGE_TOT / 4, 256, 0, stream>>>(xlb, xrb, g1_at, ei, sc, menc);
  k_edge_p<<<N_EDGE_TOT * 8 / 256, 256, 0, stream>>>(sc, menc, ei, pbuf, den);
  k_aggregate<1><<<N_NODES, 256, 0, stream>>>(xlb, pbuf, den, rp, el, ei, g1_bi, g1o);

  // --- GAT layer 2 ---
  k_gemm<0><<<dim3(32, 8), 256, 0, stream>>>(g1o, g2_wl, g2_bl, xlb, 2048, 512, 512);
  k_gemm<0><<<dim3(32, 8), 256, 0, stream>>>(g1o, g2_wr, g2_br, xrb, 2048, 512, 512);
  hipMemsetAsync(menc, 0, 2048 * 8 * sizeof(unsigned), stream);
  hipMemsetAsync(den, 0, 2048 * 8 * sizeof(float), stream);
  k_edge_score<<<N_EDGE_TOT / 4, 256, 0, stream>>>(xlb, xrb, g2_at, ei, sc, menc);
  k_edge_p<<<N_EDGE_TOT * 8 / 256, 256, 0, stream>>>(sc, menc, ei, pbuf, den);
  k_aggregate<0><<<N_NODES, 256, 0, stream>>>(xlb, pbuf, den, rp, el, ei, g2_bi, g2o);

  // --- classifier + loss/acc ---
  k_gemm<1><<<dim3(32, 1), 256, 0, stream>>>(g2o, cl_w1, cl_b1, hc1, 2048, 64, 512);
  k_gemm<1><<<dim3(32, 1), 256, 0, stream>>>(hc1, cl_w2, cl_b2, hc2, 2048, 64, 64);
  k_final<<<1, 1024, 0, stream>>>(hc2, cl_w3, cl_b3, y, out);
}

// Round 2
// 637.373 us; speedup vs baseline: 6.7522x; 6.7522x over previous
//
#include <hip/hip_runtime.h>
#include <cstdint>
#include <cstddef>

#define N_NODES 2048
#define N_PTS 256
#define N_EDGE 32768
#define N_EDGE_TOT (N_EDGE + N_NODES)  // 34816, with self-loops appended
#define NPG 32                          // nodes per graph (2048/64)

typedef __attribute__((ext_vector_type(8))) short bfx8;
typedef __attribute__((ext_vector_type(4))) float f32x4;
typedef unsigned short ushort_t;

#define MFMA16(a, b, c) __builtin_amdgcn_mfma_f32_16x16x32_bf16(a, b, c, 0, 0, 0)

// ---------- helpers ----------
__device__ inline unsigned fenc(float x) {
  unsigned u = __float_as_uint(x);
  return (u & 0x80000000u) ? ~u : (u | 0x80000000u);
}
__device__ inline float fdec(unsigned u) {
  return __uint_as_float((u & 0x80000000u) ? (u ^ 0x80000000u) : ~u);
}
__device__ inline int e_src(const int* ei, int e) { return e < N_EDGE ? ei[e] : e - N_EDGE; }
__device__ inline int e_dst(const int* ei, int e) { return e < N_EDGE ? ei[N_EDGE + e] : e - N_EDGE; }

__device__ inline ushort_t bf16_rtne(float v) {
  unsigned u = __float_as_uint(v);
  return (ushort_t)((u + 0x7fffu + ((u >> 16) & 1u)) >> 16);
}
__device__ inline void split2(float v, ushort_t& h, ushort_t& l) {
  h = bf16_rtne(v);
  float hf = __uint_as_float(((unsigned)h) << 16);
  l = bf16_rtne(v - hf);
}

// ---------- graph build: CSR of in-edges grouped by dst ----------
__global__ void k_hist(const int* __restrict__ ei, int* __restrict__ cnt) {
  int e = blockIdx.x * 256 + threadIdx.x;
  if (e >= N_EDGE_TOT) return;
  atomicAdd(&cnt[e_dst(ei, e)], 1);
}

__global__ __launch_bounds__(256) void k_scan(const int* __restrict__ cnt, int* __restrict__ row_ptr) {
  __shared__ int sS[256];
  const int t = threadIdx.x;
  int v[8]; int s = 0;
#pragma unroll
  for (int i = 0; i < 8; i++) { v[i] = cnt[t * 8 + i]; s += v[i]; }
  sS[t] = s;
  __syncthreads();
  for (int off = 1; off < 256; off <<= 1) {
    int x = 0;
    if (t >= off) x = sS[t - off];
    __syncthreads();
    sS[t] += x;
    __syncthreads();
  }
  int run = sS[t] - s;  // exclusive prefix
#pragma unroll
  for (int i = 0; i < 8; i++) { row_ptr[t * 8 + i] = run; run += v[i]; }
  if (t == 255) row_ptr[2048] = run;
}

__global__ void k_scatter(const int* __restrict__ ei, const int* __restrict__ row_ptr,
                          int* __restrict__ cur, int* __restrict__ edge_list) {
  int e = blockIdx.x * 256 + threadIdx.x;
  if (e >= N_EDGE_TOT) return;
  int d = e_dst(ei, e);
  int pos = row_ptr[d] + atomicAdd(&cur[d], 1);
  edge_list[pos] = e;
}

// ---------- weight prep: transpose + split f32 -> (hi,lo) bf16 ----------
// w2[64][64] -> w2t[n][k]; w3 same; w4[64][128] -> w4t[128][64]; w5[128][512] -> w5t[512][128]
__global__ void k_prep(const float* __restrict__ w2, const float* __restrict__ w3,
                       const float* __restrict__ w4, const float* __restrict__ w5,
                       ushort_t* __restrict__ w2th, ushort_t* __restrict__ w2tl,
                       ushort_t* __restrict__ w3th, ushort_t* __restrict__ w3tl,
                       ushort_t* __restrict__ w4th, ushort_t* __restrict__ w4tl,
                       ushort_t* __restrict__ w5th, ushort_t* __restrict__ w5tl) {
  int i = blockIdx.x * 256 + threadIdx.x;
  ushort_t h, l;
  if (i < 4096) {
    int k = i >> 6, n = i & 63;
    split2(w2[i], h, l);
    w2th[n * 64 + k] = h; w2tl[n * 64 + k] = l;
  } else if (i < 8192) {
    int j = i - 4096; int k = j >> 6, n = j & 63;
    split2(w3[j], h, l);
    w3th[n * 64 + k] = h; w3tl[n * 64 + k] = l;
  } else if (i < 16384) {
    int j = i - 8192; int k = j >> 7, n = j & 127;
    split2(w4[j], h, l);
    w4th[n * 64 + k] = h; w4tl[n * 64 + k] = l;
  } else if (i < 81920) {
    int j = i - 16384; int k = j >> 9, n = j & 511;
    split2(w5[j], h, l);
    w5th[n * 128 + k] = h; w5tl[n * 128 + k] = l;
  }
}

// ---------- PointNet fused, split-bf16 MFMA (3-pass), LDS-resident ----------
// One block per node (256 pts), 512 threads = 8 waves.
// Phase 1: 8 chunks of 32 points through L1(VALU)->L2->L3->L4 (MFMA), h4 in LDS.
// Phase 2: L5 (K=128 -> N=512) MFMA with w5 frags cached in VGPRs + fused relu/maxpool.
__global__ __launch_bounds__(512, 2) void k_pointnet(
    const float* __restrict__ pcd, const float* __restrict__ w1,
    const ushort_t* __restrict__ w2th, const ushort_t* __restrict__ w2tl,
    const ushort_t* __restrict__ w3th, const ushort_t* __restrict__ w3tl,
    const ushort_t* __restrict__ w4th, const ushort_t* __restrict__ w4tl,
    const ushort_t* __restrict__ w5th, const ushort_t* __restrict__ w5tl,
    float* __restrict__ xcat) {
  __shared__ ushort_t sH4H[256 * 128];  // 64 KB, swizzled [row][128]
  __shared__ ushort_t sH4L[256 * 128];  // 64 KB
  __shared__ ushort_t sBAH[32 * 64];    // 4 KB ping
  __shared__ ushort_t sBAL[32 * 64];
  __shared__ ushort_t sBBH[32 * 64];    // 4 KB pong
  __shared__ ushort_t sBBL[32 * 64];
  __shared__ float sP[256 * 3];
  __shared__ float sW1[3 * 64];

  char* H4H = (char*)sH4H; char* H4L = (char*)sH4L;
  char* BAH = (char*)sBAH; char* BAL = (char*)sBAL;
  char* BBH = (char*)sBBH; char* BBL = (char*)sBBL;

  const int t = threadIdx.x;
  const int node = blockIdx.x;
  const int w = t >> 6;
  const int lane = t & 63;
  const int l15 = lane & 15;
  const int kg = lane >> 4;  // 0..3

  // stage pcd + w1
  for (int i = t; i < 768; i += 512) sP[i] = pcd[(size_t)node * 768 + i];
  for (int i = t; i < 192; i += 512) sW1[i] = w1[i];

  // cache per-wave B-fragments for L2-L4 in VGPRs (loaded once)
  const int rt14 = w >> 2;  // 0..1
  const int ct14 = w & 3;   // 0..3
  bfx8 b2h[2], b2l[2], b3h[2], b3l[2], b4h[2][2], b4l[2][2];
#pragma unroll
  for (int ks = 0; ks < 2; ks++) {
    {
      int col = ct14 * 16 + l15;
      int k = ks * 32 + kg * 8;
      b2h[ks] = *(const bfx8*)(w2th + col * 64 + k);
      b2l[ks] = *(const bfx8*)(w2tl + col * 64 + k);
      b3h[ks] = *(const bfx8*)(w3th + col * 64 + k);
      b3l[ks] = *(const bfx8*)(w3tl + col * 64 + k);
    }
#pragma unroll
    for (int u = 0; u < 2; u++) {
      int col = (ct14 * 2 + u) * 16 + l15;
      int k = ks * 32 + kg * 8;
      b4h[u][ks] = *(const bfx8*)(w4th + col * 64 + k);
      b4l[u][ks] = *(const bfx8*)(w4tl + col * 64 + k);
    }
  }
  __syncthreads();

  // ---------------- phase 1: L1-L4 over 8 chunks of 32 points ----------------
  for (int c = 0; c < 8; c++) {
    // L1 (VALU): 32 rows x 64 cols, write BA (swizzled hi/lo bf16)
    {
      int r = t >> 4, cix = t & 15;
      const float* p = &sP[(c * 32 + r) * 3];
      float p0 = p[0], p1 = p[1], p2 = p[2];
#pragma unroll
      for (int j = 0; j < 4; j++) {
        int col = cix * 4 + j;
        float v = fmaf(p0, sW1[col], fmaf(p1, sW1[64 + col], p2 * sW1[128 + col]));
        v = fmaxf(v, 0.0f);
        ushort_t h, l; split2(v, h, l);
        int off = (r * 128 + col * 2) ^ ((r & 7) << 4);
        *(ushort_t*)(BAH + off) = h;
        *(ushort_t*)(BAL + off) = l;
      }
    }
    __syncthreads();
    // L2: BA -> BB
    {
      f32x4 acc = {0.f, 0.f, 0.f, 0.f};
#pragma unroll
      for (int ks = 0; ks < 2; ks++) {
        int row = rt14 * 16 + l15;
        int k0 = ks * 32 + kg * 8;
        int offb = (row * 128 + k0 * 2) ^ ((row & 7) << 4);
        bfx8 ah = *(const bfx8*)(BAH + offb);
        bfx8 al = *(const bfx8*)(BAL + offb);
        acc = MFMA16(ah, b2h[ks], acc);
        acc = MFMA16(al, b2h[ks], acc);
        acc = MFMA16(ah, b2l[ks], acc);
      }
#pragma unroll
      for (int j = 0; j < 4; j++) {
        int row = rt14 * 16 + kg * 4 + j;
        int col = ct14 * 16 + l15;
        float v = fmaxf(acc[j], 0.0f);
        ushort_t h, l; split2(v, h, l);
        int off = (row * 128 + col * 2) ^ ((row & 7) << 4);
        *(ushort_t*)(BBH + off) = h;
        *(ushort_t*)(BBL + off) = l;
      }
    }
    __syncthreads();
    // L3: BB -> BA
    {
      f32x4 acc = {0.f, 0.f, 0.f, 0.f};
#pragma unroll
      for (int ks = 0; ks < 2; ks++) {
        int row = rt14 * 16 + l15;
        int k0 = ks * 32 + kg * 8;
        int offb = (row * 128 + k0 * 2) ^ ((row & 7) << 4);
        bfx8 ah = *(const bfx8*)(BBH + offb);
        bfx8 al = *(const bfx8*)(BBL + offb);
        acc = MFMA16(ah, b3h[ks], acc);
        acc = MFMA16(al, b3h[ks], acc);
        acc = MFMA16(ah, b3l[ks], acc);
      }
#pragma unroll
      for (int j = 0; j < 4; j++) {
        int row = rt14 * 16 + kg * 4 + j;
        int col = ct14 * 16 + l15;
        float v = fmaxf(acc[j], 0.0f);
        ushort_t h, l; split2(v, h, l);
        int off = (row * 128 + col * 2) ^ ((row & 7) << 4);
        *(ushort_t*)(BAH + off) = h;
        *(ushort_t*)(BAL + off) = l;
      }
    }
    __syncthreads();
    // L4: BA -> H4 rows [c*32, c*32+32)
    {
      f32x4 acc[2];
      acc[0] = (f32x4){0.f, 0.f, 0.f, 0.f};
      acc[1] = (f32x4){0.f, 0.f, 0.f, 0.f};
#pragma unroll
      for (int ks = 0; ks < 2; ks++) {
        int row = rt14 * 16 + l15;
        int k0 = ks * 32 + kg * 8;
        int offb = (row * 128 + k0 * 2) ^ ((row & 7) << 4);
        bfx8 ah = *(const bfx8*)(BAH + offb);
        bfx8 al = *(const bfx8*)(BAL + offb);
#pragma unroll
        for (int u = 0; u < 2; u++) {
          acc[u] = MFMA16(ah, b4h[u][ks], acc[u]);
          acc[u] = MFMA16(al, b4h[u][ks], acc[u]);
          acc[u] = MFMA16(ah, b4l[u][ks], acc[u]);
        }
      }
#pragma unroll
      for (int u = 0; u < 2; u++)
#pragma unroll
        for (int j = 0; j < 4; j++) {
          int row = c * 32 + rt14 * 16 + kg * 4 + j;
          int col = (ct14 * 2 + u) * 16 + l15;  // feature 0..127
          float v = fmaxf(acc[u][j], 0.0f);
          ushort_t h, l; split2(v, h, l);
          int off = (row * 256 + col * 2) ^ ((row & 7) << 4);
          *(ushort_t*)(H4H + off) = h;
          *(ushort_t*)(H4L + off) = l;
        }
    }
    __syncthreads();
  }

  // ---------------- phase 2: L5 (256x512x128) + relu + maxpool ----------------
  __builtin_amdgcn_sched_barrier(0);  // keep b5 loads out of phase 1 (VGPR pressure)
  bfx8 b5h[4][4], b5l[4][4];  // [ks][ct]
  const int c0 = w * 64;
#pragma unroll
  for (int ks = 0; ks < 4; ks++)
#pragma unroll
    for (int ct = 0; ct < 4; ct++) {
      int col = c0 + ct * 16 + l15;
      int k = ks * 32 + kg * 8;
      b5h[ks][ct] = *(const bfx8*)(w5th + col * 128 + k);
      b5l[ks][ct] = *(const bfx8*)(w5tl + col * 128 + k);
    }
  float runmax[4] = {0.f, 0.f, 0.f, 0.f};  // relu => max >= 0
  for (int rc = 0; rc < 8; rc++) {
    f32x4 acc[2][4];
#pragma unroll
    for (int rt = 0; rt < 2; rt++)
#pragma unroll
      for (int ct = 0; ct < 4; ct++) acc[rt][ct] = (f32x4){0.f, 0.f, 0.f, 0.f};
#pragma unroll
    for (int ks = 0; ks < 4; ks++) {
      bfx8 ah[2], al[2];
#pragma unroll
      for (int rt = 0; rt < 2; rt++) {
        int row = rc * 32 + rt * 16 + l15;
        int k0 = ks * 32 + kg * 8;
        int off = (row * 256 + k0 * 2) ^ ((row & 7) << 4);
        ah[rt] = *(const bfx8*)(H4H + off);
        al[rt] = *(const bfx8*)(H4L + off);
      }
#pragma unroll
      for (int ct = 0; ct < 4; ct++)
#pragma unroll
        for (int rt = 0; rt < 2; rt++) {
          acc[rt][ct] = MFMA16(ah[rt], b5h[ks][ct], acc[rt][ct]);
          acc[rt][ct] = MFMA16(al[rt], b5h[ks][ct], acc[rt][ct]);
          acc[rt][ct] = MFMA16(ah[rt], b5l[ks][ct], acc[rt][ct]);
        }
    }
#pragma unroll
    for (int ct = 0; ct < 4; ct++)
#pragma unroll
      for (int rt = 0; rt < 2; rt++)
#pragma unroll
        for (int j = 0; j < 4; j++)
          runmax[ct] = fmaxf(runmax[ct], acc[rt][ct][j]);
  }
#pragma unroll
  for (int ct = 0; ct < 4; ct++) {
    float m = runmax[ct];
    m = fmaxf(m, __shfl_xor(m, 16));
    m = fmaxf(m, __shfl_xor(m, 32));
    if (lane < 16) xcat[(size_t)node * 1024 + c0 + ct * 16 + lane] = m;
  }
}

// ---------- multi-feature MLP part 1 (vd @ mf_w1 + b1, relu) into RIGHT half ----------
__global__ void k_vdf(const float* __restrict__ vol, const float* __restrict__ dist,
                      const float* __restrict__ ec, const float* __restrict__ w1,
                      const float* __restrict__ b1, float* __restrict__ xcat) {
  int idx = blockIdx.x * 256 + threadIdx.x;  // 2048*512
  int n = idx >> 9, j = idx & 511;
  float v = vol[n] * w1[j] + dist[n] * w1[512 + j] + ec[n] * w1[1024 + j] + b1[j];
  xcat[(size_t)n * 1024 + 512 + j] = fmaxf(v, 0.0f);
}

// ---------- generic f32 GEMM: C = act(A[M,K] @ W[K,N] + bias), tiles 64x64x16 ----------
template <int ACT>
__global__ __launch_bounds__(256) void k_gemm(const float* __restrict__ A,
                                              const float* __restrict__ W,
                                              const float* __restrict__ bias,
                                              float* __restrict__ C, int M, int N, int K) {
  __shared__ float sA[64][17];
  __shared__ float sW[16][64];
  const int t = threadIdx.x;
  const int row0 = blockIdx.x * 64, col0 = blockIdx.y * 64;
  const int tr = t >> 4, tc = t & 15;
  const int la_r = t >> 2, la_c = (t & 3) * 4;
  const int lw_r = t >> 4, lw_c = (t & 15) * 4;
  float acc[4][4] = {};
  for (int kb = 0; kb < K; kb += 16) {
    __syncthreads();
    float4 av = *(const float4*)(A + (size_t)(row0 + la_r) * K + kb + la_c);
    sA[la_r][la_c + 0] = av.x; sA[la_r][la_c + 1] = av.y;
    sA[la_r][la_c + 2] = av.z; sA[la_r][la_c + 3] = av.w;
    float4 wv = *(const float4*)(W + (size_t)(kb + lw_r) * N + col0 + lw_c);
    *(float4*)&sW[lw_r][lw_c] = wv;
    __syncthreads();
#pragma unroll
    for (int kk = 0; kk < 16; kk++) {
      float a0 = sA[tr * 4 + 0][kk], a1 = sA[tr * 4 + 1][kk];
      float a2 = sA[tr * 4 + 2][kk], a3 = sA[tr * 4 + 3][kk];
      float4 w4 = *(const float4*)&sW[kk][tc * 4];
      acc[0][0] = fmaf(a0, w4.x, acc[0][0]); acc[0][1] = fmaf(a0, w4.y, acc[0][1]);
      acc[0][2] = fmaf(a0, w4.z, acc[0][2]); acc[0][3] = fmaf(a0, w4.w, acc[0][3]);
      acc[1][0] = fmaf(a1, w4.x, acc[1][0]); acc[1][1] = fmaf(a1, w4.y, acc[1][1]);
      acc[1][2] = fmaf(a1, w4.z, acc[1][2]); acc[1][3] = fmaf(a1, w4.w, acc[1][3]);
      acc[2][0] = fmaf(a2, w4.x, acc[2][0]); acc[2][1] = fmaf(a2, w4.y, acc[2][1]);
      acc[2][2] = fmaf(a2, w4.z, acc[2][2]); acc[2][3] = fmaf(a2, w4.w, acc[2][3]);
      acc[3][0] = fmaf(a3, w4.x, acc[3][0]); acc[3][1] = fmaf(a3, w4.y, acc[3][1]);
      acc[3][2] = fmaf(a3, w4.z, acc[3][2]); acc[3][3] = fmaf(a3, w4.w, acc[3][3]);
    }
  }
#pragma unroll
  for (int i = 0; i < 4; i++) {
    int r = row0 + tr * 4 + i;
#pragma unroll
    for (int j = 0; j < 4; j++) {
      int c = col0 + tc * 4 + j;
      float v = acc[i][j] + bias[c];
      if (ACT == 1) v = fmaxf(v, 0.0f);
      C[(size_t)r * N + c] = v;
    }
  }
}

// ---------- GATv2 edge scores + segment max (one wave per edge) ----------
__global__ void k_edge_score(const float* __restrict__ xl, const float* __restrict__ xr,
                             const float* __restrict__ att, const int* __restrict__ ei,
                             float* __restrict__ score, unsigned* __restrict__ m_enc) {
  __shared__ float sAtt[512];
  const int t = threadIdx.x;
  for (int i = t; i < 512; i += 256) sAtt[i] = att[i];
  __syncthreads();
  const int wv = t >> 6, l = t & 63;
  const int e = blockIdx.x * 4 + wv;
  if (e >= N_EDGE_TOT) return;
  const int s = e_src(ei, e), d = e_dst(ei, e);
  const float* xls = xl + (size_t)s * 512;
  const float* xrd = xr + (size_t)d * 512;
  float ps[8];
#pragma unroll
  for (int h = 0; h < 8; h++) {
    float v = xls[h * 64 + l] + xrd[h * 64 + l];
    v = v > 0.0f ? v : 0.2f * v;  // leaky_relu(0.2)
    ps[h] = v * sAtt[h * 64 + l];
  }
#pragma unroll
  for (int off = 1; off < 64; off <<= 1)
#pragma unroll
    for (int h = 0; h < 8; h++) ps[h] += __shfl_xor(ps[h], off);
  if (l == 0) {
    size_t base = (size_t)e * 8;
#pragma unroll
    for (int h = 0; h < 8; h++) {
      score[base + h] = ps[h];
      atomicMax(&m_enc[d * 8 + h], fenc(ps[h]));
    }
  }
}

// ---------- p = exp(score - m[dst]); denom = segment_sum ----------
__global__ void k_edge_p(const float* __restrict__ score, const unsigned* __restrict__ m_enc,
                         const int* __restrict__ ei, float* __restrict__ p,
                         float* __restrict__ denom) {
  int idx = blockIdx.x * 256 + threadIdx.x;
  if (idx >= N_EDGE_TOT * 8) return;
  int e = idx >> 3, h = idx & 7;
  int d = e_dst(ei, e);
  float m = fdec(m_enc[d * 8 + h]);
  float pv = expf(score[idx] - m);
  p[idx] = pv;
  atomicAdd(&denom[d * 8 + h], pv);
}

// ---------- out[n] = sum_e alpha * xl[src] + bias (CSR, no atomics) ----------
template <int ACT>
__global__ __launch_bounds__(256) void k_aggregate(
    const float* __restrict__ xl, const float* __restrict__ p, const float* __restrict__ denom,
    const int* __restrict__ row_ptr, const int* __restrict__ edge_list,
    const int* __restrict__ ei, const float* __restrict__ bias, float* __restrict__ out) {
  __shared__ float sInv[8];
  const int n = blockIdx.x, t = threadIdx.x;
  if (t < 8) sInv[t] = 1.0f / denom[n * 8 + t];
  __syncthreads();
  const int f0 = t, f1 = t + 256;
  const int h0 = f0 >> 6, h1 = f1 >> 6;
  float acc0 = 0.0f, acc1 = 0.0f;
  const int beg = row_ptr[n], end = row_ptr[n + 1];
  for (int i = beg; i < end; i++) {
    const int e = edge_list[i];
    const int s = e_src(ei, e);
    const float* xs = xl + (size_t)s * 512;
    const float a0 = p[(size_t)e * 8 + h0] * sInv[h0];
    const float a1 = p[(size_t)e * 8 + h1] * sInv[h1];
    acc0 = fmaf(a0, xs[f0], acc0);
    acc1 = fmaf(a1, xs[f1], acc1);
  }
  float v0 = acc0 + bias[f0], v1 = acc1 + bias[f1];
  if (ACT == 1) { v0 = fmaxf(v0, 0.0f); v1 = fmaxf(v1, 0.0f); }
  out[(size_t)n * 512 + f0] = v0;
  out[(size_t)n * 512 + f1] = v1;
}

// ---------- logits + BCE loss + per-graph argmax hits ----------
__global__ __launch_bounds__(1024) void k_final(const float* __restrict__ hc2,
                                                const float* __restrict__ w3,
                                                const float* __restrict__ b3,
                                                const float* __restrict__ y,
                                                float* __restrict__ out) {
  __shared__ float sL[2048];
  __shared__ float sRed[1024];
  __shared__ float sW[64];
  const int t = threadIdx.x;
  if (t < 64) sW[t] = w3[t];
  __syncthreads();
  float lp = 0.0f;
  for (int n = t; n < 2048; n += 1024) {
    const float4* r = (const float4*)(hc2 + (size_t)n * 64);
    float a = 0.0f;
#pragma unroll
    for (int k = 0; k < 16; k++) {
      float4 v = r[k];
      a += v.x * sW[4 * k] + v.y * sW[4 * k + 1] + v.z * sW[4 * k + 2] + v.w * sW[4 * k + 3];
    }
    a += b3[0];
    sL[n] = a;
    lp += fmaxf(a, 0.0f) - a * y[n] + log1pf(expf(-fabsf(a)));
  }
  sRed[t] = lp;
  __syncthreads();
  for (int off = 512; off > 0; off >>= 1) {
    if (t < off) sRed[t] += sRed[t + off];
    __syncthreads();
  }
  if (t == 0) out[0] = sRed[0] * (1.0f / 2048.0f);
  __syncthreads();
  float hit = 0.0f;
  if (t < 64) {
    const int base = t * NPG;
    float bl = sL[base]; int bi = 0;
    float by = y[base];  int byi = 0;
    for (int i = 1; i < NPG - 1; i++) {  // [:, :-1] -> 31 entries, first-max tie rule
      float v = sL[base + i];
      if (v > bl) { bl = v; bi = i; }
      float w = y[base + i];
      if (w > by) { by = w; byi = i; }
    }
    hit = (bi == byi) ? 1.0f : 0.0f;
  }
  __syncthreads();
  sRed[t] = hit;
  __syncthreads();
  for (int off = 512; off > 0; off >>= 1) {
    if (t < off) sRed[t] += sRed[t + off];
    __syncthreads();
  }
  if (t == 0) out[1] = sRed[0] * (1.0f / 64.0f);
}

// ---------- workspace layout (float units) ----------
constexpr size_t OFF_XCAT = 0;                                  // [2048,1024]
constexpr size_t OFF_X1   = OFF_XCAT + (size_t)2048 * 1024;     // [2048,512]
constexpr size_t OFF_XL   = OFF_X1 + (size_t)2048 * 512;
constexpr size_t OFF_XR   = OFF_XL + (size_t)2048 * 512;
constexpr size_t OFF_G1   = OFF_XR + (size_t)2048 * 512;
constexpr size_t OFF_G2   = OFF_G1 + (size_t)2048 * 512;
constexpr size_t OFF_HC1  = OFF_G2 + (size_t)2048 * 512;        // [2048,64]
constexpr size_t OFF_HC2  = OFF_HC1 + (size_t)2048 * 64;
constexpr size_t OFF_SC   = OFF_HC2 + (size_t)2048 * 64;        // [34816,8]
constexpr size_t OFF_P    = OFF_SC + (size_t)N_EDGE_TOT * 8;
constexpr size_t OFF_M    = OFF_P + (size_t)N_EDGE_TOT * 8;     // u32 [2048,8]
constexpr size_t OFF_DEN  = OFF_M + (size_t)2048 * 8;
constexpr size_t OFF_RP   = OFF_DEN + (size_t)2048 * 8;         // int [2052]
constexpr size_t OFF_CNT  = OFF_RP + 2052;                      // int [2048]
constexpr size_t OFF_EL   = OFF_CNT + 2048;                     // int [34816]
constexpr size_t OFF_USH  = OFF_EL + 34816;                     // ushort regions start (16B aligned)

extern "C" void kernel_launch(void* const* d_in, const int* in_sizes, int n_in,
                              void* d_out, int out_size, void* d_ws, size_t ws_size,
                              hipStream_t stream) {
  const float* pcd   = (const float*)d_in[0];
  const float* vol   = (const float*)d_in[1];
  const float* dist  = (const float*)d_in[2];
  const float* ecnt  = (const float*)d_in[3];
  const float* y     = (const float*)d_in[4];
  const float* pn_w1 = (const float*)d_in[5];
  const float* pn_w2 = (const float*)d_in[6];
  const float* pn_w3 = (const float*)d_in[7];
  const float* pn_w4 = (const float*)d_in[8];
  const float* pn_w5 = (const float*)d_in[9];
  const float* mf_w1 = (const float*)d_in[10];
  const float* mf_b1 = (const float*)d_in[11];
  const float* mf_w2 = (const float*)d_in[12];
  const float* mf_b2 = (const float*)d_in[13];
  const float* g1_wl = (const float*)d_in[14];
  const float* g1_bl = (const float*)d_in[15];
  const float* g1_wr = (const float*)d_in[16];
  const float* g1_br = (const float*)d_in[17];
  const float* g1_at = (const float*)d_in[18];
  const float* g1_bi = (const float*)d_in[19];
  const float* g2_wl = (const float*)d_in[20];
  const float* g2_bl = (const float*)d_in[21];
  const float* g2_wr = (const float*)d_in[22];
  const float* g2_br = (const float*)d_in[23];
  const float* g2_at = (const float*)d_in[24];
  const float* g2_bi = (const float*)d_in[25];
  const float* cl_w1 = (const float*)d_in[26];
  const float* cl_b1 = (const float*)d_in[27];
  const float* cl_w2 = (const float*)d_in[28];
  const float* cl_b2 = (const float*)d_in[29];
  const float* cl_w3 = (const float*)d_in[30];
  const float* cl_b3 = (const float*)d_in[31];
  const int*   ei    = (const int*)d_in[32];
  float* out = (float*)d_out;
  float* ws  = (float*)d_ws;

  float* xcat = ws + OFF_XCAT;
  float* x1   = ws + OFF_X1;
  float* xlb  = ws + OFF_XL;
  float* xrb  = ws + OFF_XR;
  float* g1o  = ws + OFF_G1;
  float* g2o  = ws + OFF_G2;
  float* hc1  = ws + OFF_HC1;
  float* hc2  = ws + OFF_HC2;
  float* sc   = ws + OFF_SC;
  float* pbuf = ws + OFF_P;
  unsigned* menc = (unsigned*)(ws + OFF_M);
  float* den  = ws + OFF_DEN;
  int* rp     = (int*)(ws + OFF_RP);
  int* cnt    = (int*)(ws + OFF_CNT);
  int* el     = (int*)(ws + OFF_EL);
  ushort_t* ush = (ushort_t*)(ws + OFF_USH);
  ushort_t* w2th = ush;
  ushort_t* w2tl = ush + 4096;
  ushort_t* w3th = ush + 8192;
  ushort_t* w3tl = ush + 12288;
  ushort_t* w4th = ush + 16384;
  ushort_t* w4tl = ush + 24576;
  ushort_t* w5th = ush + 32768;
  ushort_t* w5tl = ush + 98304;

  // --- build CSR by dst (shared by both GAT layers) ---
  hipMemsetAsync(cnt, 0, 2048 * sizeof(int), stream);
  k_hist<<<(N_EDGE_TOT + 255) / 256, 256, 0, stream>>>(ei, cnt);
  k_scan<<<1, 256, 0, stream>>>(cnt, rp);
  hipMemsetAsync(cnt, 0, 2048 * sizeof(int), stream);
  k_scatter<<<(N_EDGE_TOT + 255) / 256, 256, 0, stream>>>(ei, rp, cnt, el);

  // --- weight prep + PointNet + multi-feature ---
  k_prep<<<320, 256, 0, stream>>>(pn_w2, pn_w3, pn_w4, pn_w5,
                                  w2th, w2tl, w3th, w3tl, w4th, w4tl, w5th, w5tl);
  k_pointnet<<<N_NODES, 512, 0, stream>>>(pcd, pn_w1, w2th, w2tl, w3th, w3tl,
                                          w4th, w4tl, w5th, w5tl, xcat);
  k_vdf<<<2048 * 512 / 256, 256, 0, stream>>>(vol, dist, ecnt, mf_w1, mf_b1, xcat);
  k_gemm<1><<<dim3(32, 8), 256, 0, stream>>>(xcat, mf_w2, mf_b2, x1, 2048, 512, 1024);

  // --- GAT layer 1 ---
  k_gemm<0><<<dim3(32, 8), 256, 0, stream>>>(x1, g1_wl, g1_bl, xlb, 2048, 512, 512);
  k_gemm<0><<<dim3(32, 8), 256, 0, stream>>>(x1, g1_wr, g1_br, xrb, 2048, 512, 512);
  hipMemsetAsync(menc, 0, 2048 * 8 * sizeof(unsigned), stream);
  hipMemsetAsync(den, 0, 2048 * 8 * sizeof(float), stream);
  k_edge_score<<<N_EDGE_TOT / 4, 256, 0, stream>>>(xlb, xrb, g1_at, ei, sc, menc);
  k_edge_p<<<N_EDGE_TOT * 8 / 256, 256, 0, stream>>>(sc, menc, ei, pbuf, den);
  k_aggregate<1><<<N_NODES, 256, 0, stream>>>(xlb, pbuf, den, rp, el, ei, g1_bi, g1o);

  // --- GAT layer 2 ---
  k_gemm<0><<<dim3(32, 8), 256, 0, stream>>>(g1o, g2_wl, g2_bl, xlb, 2048, 512, 512);
  k_gemm<0><<<dim3(32, 8), 256, 0, stream>>>(g1o, g2_wr, g2_br, xrb, 2048, 512, 512);
  hipMemsetAsync(menc, 0, 2048 * 8 * sizeof(unsigned), stream);
  hipMemsetAsync(den, 0, 2048 * 8 * sizeof(float), stream);
  k_edge_score<<<N_EDGE_TOT / 4, 256, 0, stream>>>(xlb, xrb, g2_at, ei, sc, menc);
  k_edge_p<<<N_EDGE_TOT * 8 / 256, 256, 0, stream>>>(sc, menc, ei, pbuf, den);
  k_aggregate<0><<<N_NODES, 256, 0, stream>>>(xlb, pbuf, den, rp, el, ei, g2_bi, g2o);

  // --- classifier + loss/acc ---
  k_gemm<1><<<dim3(32, 1), 256, 0, stream>>>(g2o, cl_w1, cl_b1, hc1, 2048, 64, 512);
  k_gemm<1><<<dim3(32, 1), 256, 0, stream>>>(hc1, cl_w2, cl_b2, hc2, 2048, 64, 64);
  k_final<<<1, 1024, 0, stream>>>(hc2, cl_w3, cl_b3, y, out);
}

// Round 3
// 577.135 us; speedup vs baseline: 7.4570x; 1.1044x over previous
//
#include <hip/hip_runtime.h>
#include <cstdint>
#include <cstddef>

#define N_NODES 2048
#define N_PTS 256
#define N_EDGE 32768
#define N_EDGE_TOT (N_EDGE + N_NODES)  // 34816, with self-loops appended
#define NPG 32                          // nodes per graph (2048/64)

typedef __attribute__((ext_vector_type(8))) short bfx8;
typedef __attribute__((ext_vector_type(4))) float f32x4;
typedef unsigned short ushort_t;

#define MFMA16(a, b, c) __builtin_amdgcn_mfma_f32_16x16x32_bf16(a, b, c, 0, 0, 0)

// ---------- helpers ----------
__device__ inline unsigned fenc(float x) {
  unsigned u = __float_as_uint(x);
  return (u & 0x80000000u) ? ~u : (u | 0x80000000u);
}
__device__ inline float fdec(unsigned u) {
  return __uint_as_float((u & 0x80000000u) ? (u ^ 0x80000000u) : ~u);
}
__device__ inline int e_src(const int* ei, int e) { return e < N_EDGE ? ei[e] : e - N_EDGE; }
__device__ inline int e_dst(const int* ei, int e) { return e < N_EDGE ? ei[N_EDGE + e] : e - N_EDGE; }

__device__ inline ushort_t bf16_rtne(float v) {
  unsigned u = __float_as_uint(v);
  return (ushort_t)((u + 0x7fffu + ((u >> 16) & 1u)) >> 16);
}
__device__ inline void split2(float v, ushort_t& h, ushort_t& l) {
  h = bf16_rtne(v);
  float hf = __uint_as_float(((unsigned)h) << 16);
  l = bf16_rtne(v - hf);
}

// ---------- graph build: CSR of in-edges grouped by dst ----------
__global__ void k_hist(const int* __restrict__ ei, int* __restrict__ cnt) {
  int e = blockIdx.x * 256 + threadIdx.x;
  if (e >= N_EDGE_TOT) return;
  atomicAdd(&cnt[e_dst(ei, e)], 1);
}

__global__ __launch_bounds__(256) void k_scan(const int* __restrict__ cnt, int* __restrict__ row_ptr) {
  __shared__ int sS[256];
  const int t = threadIdx.x;
  int v[8]; int s = 0;
#pragma unroll
  for (int i = 0; i < 8; i++) { v[i] = cnt[t * 8 + i]; s += v[i]; }
  sS[t] = s;
  __syncthreads();
  for (int off = 1; off < 256; off <<= 1) {
    int x = 0;
    if (t >= off) x = sS[t - off];
    __syncthreads();
    sS[t] += x;
    __syncthreads();
  }
  int run = sS[t] - s;  // exclusive prefix
#pragma unroll
  for (int i = 0; i < 8; i++) { row_ptr[t * 8 + i] = run; run += v[i]; }
  if (t == 255) row_ptr[2048] = run;
}

__global__ void k_scatter(const int* __restrict__ ei, const int* __restrict__ row_ptr,
                          int* __restrict__ cur, int* __restrict__ edge_list) {
  int e = blockIdx.x * 256 + threadIdx.x;
  if (e >= N_EDGE_TOT) return;
  int d = e_dst(ei, e);
  int pos = row_ptr[d] + atomicAdd(&cur[d], 1);
  edge_list[pos] = e;
}

// ---------- generic weight prep: transpose [K][N] -> [N][K] + split hi/lo bf16 ----------
__global__ void k_split(const float* __restrict__ src, ushort_t* __restrict__ dh,
                        ushort_t* __restrict__ dl, int K, int N) {
  int i = blockIdx.x * 256 + threadIdx.x;
  if (i >= K * N) return;
  int k = i / N, n = i - k * N;
  ushort_t h, l;
  split2(src[i], h, l);
  dh[n * K + k] = h;
  dl[n * K + k] = l;
}

// ---------- PointNet fused, split-bf16 MFMA (3-pass), LDS-resident ----------
// One block per node (256 pts), 512 threads = 8 waves.
// L1 computed per-lane IN REGISTERS (each lane builds its own L2 A-fragment).
// Phase 1: 8 chunks of 32 points through L2->L3->L4 (MFMA), h4 in LDS.
// Phase 2: L5 (K=128 -> N=512) MFMA with w5 frags + fused relu/maxpool.
__global__ __launch_bounds__(512, 2) void k_pointnet(
    const float* __restrict__ pcd, const float* __restrict__ w1,
    const ushort_t* __restrict__ w2th, const ushort_t* __restrict__ w2tl,
    const ushort_t* __restrict__ w3th, const ushort_t* __restrict__ w3tl,
    const ushort_t* __restrict__ w4th, const ushort_t* __restrict__ w4tl,
    const ushort_t* __restrict__ w5th, const ushort_t* __restrict__ w5tl,
    float* __restrict__ xcat) {
  __shared__ ushort_t sH4H[256 * 128];  // 64 KB, swizzled
  __shared__ ushort_t sH4L[256 * 128];  // 64 KB
  __shared__ ushort_t sBAH[32 * 64];    // 4 KB
  __shared__ ushort_t sBAL[32 * 64];
  __shared__ ushort_t sBBH[32 * 64];
  __shared__ ushort_t sBBL[32 * 64];

  char* H4H = (char*)sH4H; char* H4L = (char*)sH4L;
  char* BAH = (char*)sBAH; char* BAL = (char*)sBAL;
  char* BBH = (char*)sBBH; char* BBL = (char*)sBBL;

  const int t = threadIdx.x;
  const int node = blockIdx.x;
  const int w = t >> 6;
  const int lane = t & 63;
  const int l15 = lane & 15;
  const int kg = lane >> 4;  // 0..3
  const int rt14 = w >> 2;   // 0..1
  const int ct14 = w & 3;    // 0..3

  // w1 columns this lane needs for its L2 A-fragment (k = ks*32 + kg*8 + j)
  float w1r[3][16];
#pragma unroll
  for (int r = 0; r < 3; r++)
#pragma unroll
    for (int q = 0; q < 16; q++) {
      int col = (q >> 3) * 32 + kg * 8 + (q & 7);
      w1r[r][q] = w1[r * 64 + col];
    }

  // cache per-wave B-fragments for L2-L4 in VGPRs (loaded once)
  bfx8 b2h[2], b2l[2], b3h[2], b3l[2], b4h[2][2], b4l[2][2];
#pragma unroll
  for (int ks = 0; ks < 2; ks++) {
    {
      int col = ct14 * 16 + l15;
      int k = ks * 32 + kg * 8;
      b2h[ks] = *(const bfx8*)(w2th + col * 64 + k);
      b2l[ks] = *(const bfx8*)(w2tl + col * 64 + k);
      b3h[ks] = *(const bfx8*)(w3th + col * 64 + k);
      b3l[ks] = *(const bfx8*)(w3tl + col * 64 + k);
    }
#pragma unroll
    for (int u = 0; u < 2; u++) {
      int col = (ct14 * 2 + u) * 16 + l15;
      int k = ks * 32 + kg * 8;
      b4h[u][ks] = *(const bfx8*)(w4th + col * 64 + k);
      b4l[u][ks] = *(const bfx8*)(w4tl + col * 64 + k);
    }
  }

  // ---------------- phase 1: L1(reg)+L2 -> L3 -> L4 over 8 chunks of 32 points ----
  for (int c = 0; c < 8; c++) {
    // L1 in-register + L2 MFMA -> BA
    {
      const float* pp = pcd + ((size_t)node * 256 + c * 32 + rt14 * 16 + l15) * 3;
      float p0 = pp[0], p1 = pp[1], p2 = pp[2];
      bfx8 ah[2], al[2];
#pragma unroll
      for (int ks = 0; ks < 2; ks++)
#pragma unroll
        for (int j = 0; j < 8; j++) {
          float v = fmaf(p0, w1r[0][ks * 8 + j],
                    fmaf(p1, w1r[1][ks * 8 + j], p2 * w1r[2][ks * 8 + j]));
          v = fmaxf(v, 0.0f);
          ushort_t h, l; split2(v, h, l);
          ah[ks][j] = (short)h; al[ks][j] = (short)l;
        }
      f32x4 acc = {0.f, 0.f, 0.f, 0.f};
#pragma unroll
      for (int ks = 0; ks < 2; ks++) {
        acc = MFMA16(ah[ks], b2h[ks], acc);
        acc = MFMA16(al[ks], b2h[ks], acc);
        acc = MFMA16(ah[ks], b2l[ks], acc);
      }
#pragma unroll
      for (int j = 0; j < 4; j++) {
        int row = rt14 * 16 + kg * 4 + j;
        int col = ct14 * 16 + l15;
        float v = fmaxf(acc[j], 0.0f);
        ushort_t h, l; split2(v, h, l);
        int off = (row * 128 + col * 2) ^ ((row & 7) << 4);
        *(ushort_t*)(BAH + off) = h;
        *(ushort_t*)(BAL + off) = l;
      }
    }
    __syncthreads();
    // L3: BA -> BB
    {
      f32x4 acc = {0.f, 0.f, 0.f, 0.f};
#pragma unroll
      for (int ks = 0; ks < 2; ks++) {
        int row = rt14 * 16 + l15;
        int k0 = ks * 32 + kg * 8;
        int offb = (row * 128 + k0 * 2) ^ ((row & 7) << 4);
        bfx8 ah = *(const bfx8*)(BAH + offb);
        bfx8 al = *(const bfx8*)(BAL + offb);
        acc = MFMA16(ah, b3h[ks], acc);
        acc = MFMA16(al, b3h[ks], acc);
        acc = MFMA16(ah, b3l[ks], acc);
      }
#pragma unroll
      for (int j = 0; j < 4; j++) {
        int row = rt14 * 16 + kg * 4 + j;
        int col = ct14 * 16 + l15;
        float v = fmaxf(acc[j], 0.0f);
        ushort_t h, l; split2(v, h, l);
        int off = (row * 128 + col * 2) ^ ((row & 7) << 4);
        *(ushort_t*)(BBH + off) = h;
        *(ushort_t*)(BBL + off) = l;
      }
    }
    __syncthreads();
    // L4: BB -> H4 rows [c*32, c*32+32)
    {
      f32x4 acc[2];
      acc[0] = (f32x4){0.f, 0.f, 0.f, 0.f};
      acc[1] = (f32x4){0.f, 0.f, 0.f, 0.f};
#pragma unroll
      for (int ks = 0; ks < 2; ks++) {
        int row = rt14 * 16 + l15;
        int k0 = ks * 32 + kg * 8;
        int offb = (row * 128 + k0 * 2) ^ ((row & 7) << 4);
        bfx8 ah = *(const bfx8*)(BBH + offb);
        bfx8 al = *(const bfx8*)(BBL + offb);
#pragma unroll
        for (int u = 0; u < 2; u++) {
          acc[u] = MFMA16(ah, b4h[u][ks], acc[u]);
          acc[u] = MFMA16(al, b4h[u][ks], acc[u]);
          acc[u] = MFMA16(ah, b4l[u][ks], acc[u]);
        }
      }
#pragma unroll
      for (int u = 0; u < 2; u++)
#pragma unroll
        for (int j = 0; j < 4; j++) {
          int row = c * 32 + rt14 * 16 + kg * 4 + j;
          int col = (ct14 * 2 + u) * 16 + l15;  // feature 0..127
          float v = fmaxf(acc[u][j], 0.0f);
          ushort_t h, l; split2(v, h, l);
          int off = (row * 256 + col * 2) ^ ((row & 7) << 4);
          *(ushort_t*)(H4H + off) = h;
          *(ushort_t*)(H4L + off) = l;
        }
    }
    __syncthreads();
  }

  // ---------------- phase 2: L5 (256x512x128) + relu + maxpool ----------------
  __builtin_amdgcn_sched_barrier(0);  // keep b5 loads out of phase 1 (VGPR pressure)
  bfx8 b5h[4][4], b5l[4][4];  // [ks][ct]
  const int c0 = w * 64;
#pragma unroll
  for (int ks = 0; ks < 4; ks++)
#pragma unroll
    for (int ct = 0; ct < 4; ct++) {
      int col = c0 + ct * 16 + l15;
      int k = ks * 32 + kg * 8;
      b5h[ks][ct] = *(const bfx8*)(w5th + col * 128 + k);
      b5l[ks][ct] = *(const bfx8*)(w5tl + col * 128 + k);
    }
  float runmax[4] = {0.f, 0.f, 0.f, 0.f};  // relu => max >= 0
  for (int rc = 0; rc < 8; rc++) {
    f32x4 acc[2][4];
#pragma unroll
    for (int rt = 0; rt < 2; rt++)
#pragma unroll
      for (int ct = 0; ct < 4; ct++) acc[rt][ct] = (f32x4){0.f, 0.f, 0.f, 0.f};
#pragma unroll
    for (int ks = 0; ks < 4; ks++) {
      bfx8 ah[2], al[2];
#pragma unroll
      for (int rt = 0; rt < 2; rt++) {
        int row = rc * 32 + rt * 16 + l15;
        int k0 = ks * 32 + kg * 8;
        int off = (row * 256 + k0 * 2) ^ ((row & 7) << 4);
        ah[rt] = *(const bfx8*)(H4H + off);
        al[rt] = *(const bfx8*)(H4L + off);
      }
#pragma unroll
      for (int ct = 0; ct < 4; ct++)
#pragma unroll
        for (int rt = 0; rt < 2; rt++) {
          acc[rt][ct] = MFMA16(ah[rt], b5h[ks][ct], acc[rt][ct]);
          acc[rt][ct] = MFMA16(al[rt], b5h[ks][ct], acc[rt][ct]);
          acc[rt][ct] = MFMA16(ah[rt], b5l[ks][ct], acc[rt][ct]);
        }
    }
#pragma unroll
    for (int ct = 0; ct < 4; ct++)
#pragma unroll
      for (int rt = 0; rt < 2; rt++)
#pragma unroll
        for (int j = 0; j < 4; j++)
          runmax[ct] = fmaxf(runmax[ct], acc[rt][ct][j]);
  }
#pragma unroll
  for (int ct = 0; ct < 4; ct++) {
    float m = runmax[ct];
    m = fmaxf(m, __shfl_xor(m, 16));
    m = fmaxf(m, __shfl_xor(m, 32));
    if (lane < 16) xcat[(size_t)node * 1024 + c0 + ct * 16 + lane] = m;
  }
}

// ---------- multi-feature MLP part 1 (vd @ mf_w1 + b1, relu) into RIGHT half ----------
__global__ void k_vdf(const float* __restrict__ vol, const float* __restrict__ dist,
                      const float* __restrict__ ec, const float* __restrict__ w1,
                      const float* __restrict__ b1, float* __restrict__ xcat) {
  int idx = blockIdx.x * 256 + threadIdx.x;  // 2048*512
  int n = idx >> 9, j = idx & 511;
  float v = vol[n] * w1[j] + dist[n] * w1[512 + j] + ec[n] * w1[1024 + j] + b1[j];
  xcat[(size_t)n * 1024 + 512 + j] = fmaxf(v, 0.0f);
}

// ---------- split-bf16 MFMA GEMM: C = act(A[M,K] @ W[K,N] + bias) ----------
// B pre-split/transposed in global ([N][K] hi/lo). A split on the fly.
// 256 threads = 4 waves, tile 64x64, K-step 64.
template <int ACT>
__global__ __launch_bounds__(256) void k_mgemm(const float* __restrict__ A,
                                               const ushort_t* __restrict__ Bh,
                                               const ushort_t* __restrict__ Bl,
                                               const float* __restrict__ bias,
                                               float* __restrict__ C,
                                               int M, int N, int K) {
  __shared__ ushort_t sAh[4096], sAl[4096], sBh[4096], sBl[4096];  // 32 KB
  char* pAh = (char*)sAh; char* pAl = (char*)sAl;
  char* pBh = (char*)sBh; char* pBl = (char*)sBl;
  const int t = threadIdx.x;
  const int w = t >> 6, lane = t & 63, l15 = lane & 15, kg = lane >> 4;
  const int row0 = blockIdx.x * 64, col0 = blockIdx.y * 64;
  const int sr = t >> 2;          // stage row (A) / col (B), 0..63
  const int sc = (t & 3) * 16;    // stage k offset
  const int sswz = (sr & 7) << 4;
  const int sbase = sr * 128 + sc * 2;
  f32x4 acc[4];
#pragma unroll
  for (int ct = 0; ct < 4; ct++) acc[ct] = (f32x4){0.f, 0.f, 0.f, 0.f};

  for (int kb = 0; kb < K; kb += 64) {
    __syncthreads();
    // stage A (f32 -> split hi/lo)
    {
      const float* Ap = A + (size_t)(row0 + sr) * K + kb + sc;
      bfx8 vh[2], vl[2];
#pragma unroll
      for (int i = 0; i < 4; i++) {
        float4 a = *(const float4*)(Ap + i * 4);
        ushort_t h, l;
        split2(a.x, h, l); vh[i >> 1][(i & 1) * 4 + 0] = (short)h; vl[i >> 1][(i & 1) * 4 + 0] = (short)l;
        split2(a.y, h, l); vh[i >> 1][(i & 1) * 4 + 1] = (short)h; vl[i >> 1][(i & 1) * 4 + 1] = (short)l;
        split2(a.z, h, l); vh[i >> 1][(i & 1) * 4 + 2] = (short)h; vl[i >> 1][(i & 1) * 4 + 2] = (short)l;
        split2(a.w, h, l); vh[i >> 1][(i & 1) * 4 + 3] = (short)h; vl[i >> 1][(i & 1) * 4 + 3] = (short)l;
      }
      *(bfx8*)(pAh + ((sbase) ^ sswz)) = vh[0];
      *(bfx8*)(pAh + ((sbase + 16) ^ sswz)) = vh[1];
      *(bfx8*)(pAl + ((sbase) ^ sswz)) = vl[0];
      *(bfx8*)(pAl + ((sbase + 16) ^ sswz)) = vl[1];
    }
    // stage B (already split in global)
    {
      const ushort_t* Bph = Bh + (size_t)(col0 + sr) * K + kb + sc;
      const ushort_t* Bpl = Bl + (size_t)(col0 + sr) * K + kb + sc;
      bfx8 b0 = *(const bfx8*)Bph, b1 = *(const bfx8*)(Bph + 8);
      bfx8 c0v = *(const bfx8*)Bpl, c1v = *(const bfx8*)(Bpl + 8);
      *(bfx8*)(pBh + ((sbase) ^ sswz)) = b0;
      *(bfx8*)(pBh + ((sbase + 16) ^ sswz)) = b1;
      *(bfx8*)(pBl + ((sbase) ^ sswz)) = c0v;
      *(bfx8*)(pBl + ((sbase + 16) ^ sswz)) = c1v;
    }
    __syncthreads();
#pragma unroll
    for (int ks = 0; ks < 2; ks++) {
      const int arow = w * 16 + l15;
      const int k2 = (ks * 32 + kg * 8) * 2;
      const int aoff = (arow * 128 + k2) ^ ((arow & 7) << 4);
      bfx8 ah = *(const bfx8*)(pAh + aoff);
      bfx8 al = *(const bfx8*)(pAl + aoff);
#pragma unroll
      for (int ct = 0; ct < 4; ct++) {
        const int bcol = ct * 16 + l15;
        const int boff = (bcol * 128 + k2) ^ ((bcol & 7) << 4);
        bfx8 bh = *(const bfx8*)(pBh + boff);
        bfx8 bl = *(const bfx8*)(pBl + boff);
        acc[ct] = MFMA16(ah, bh, acc[ct]);
        acc[ct] = MFMA16(al, bh, acc[ct]);
        acc[ct] = MFMA16(ah, bl, acc[ct]);
      }
    }
  }
#pragma unroll
  for (int ct = 0; ct < 4; ct++)
#pragma unroll
    for (int j = 0; j < 4; j++) {
      int r = row0 + w * 16 + kg * 4 + j;
      int cc = col0 + ct * 16 + l15;
      float v = acc[ct][j] + bias[cc];
      if (ACT == 1) v = fmaxf(v, 0.0f);
      C[(size_t)r * N + cc] = v;
    }
}

// ---------- generic f32 GEMM (fallback + small classifier layers) ----------
template <int ACT>
__global__ __launch_bounds__(256) void k_gemm(const float* __restrict__ A,
                                              const float* __restrict__ W,
                                              const float* __restrict__ bias,
                                              float* __restrict__ C, int M, int N, int K) {
  __shared__ float sA[64][17];
  __shared__ float sW[16][64];
  const int t = threadIdx.x;
  const int row0 = blockIdx.x * 64, col0 = blockIdx.y * 64;
  const int tr = t >> 4, tc = t & 15;
  const int la_r = t >> 2, la_c = (t & 3) * 4;
  const int lw_r = t >> 4, lw_c = (t & 15) * 4;
  float acc[4][4] = {};
  for (int kb = 0; kb < K; kb += 16) {
    __syncthreads();
    float4 av = *(const float4*)(A + (size_t)(row0 + la_r) * K + kb + la_c);
    sA[la_r][la_c + 0] = av.x; sA[la_r][la_c + 1] = av.y;
    sA[la_r][la_c + 2] = av.z; sA[la_r][la_c + 3] = av.w;
    float4 wv = *(const float4*)(W + (size_t)(kb + lw_r) * N + col0 + lw_c);
    *(float4*)&sW[lw_r][lw_c] = wv;
    __syncthreads();
#pragma unroll
    for (int kk = 0; kk < 16; kk++) {
      float a0 = sA[tr * 4 + 0][kk], a1 = sA[tr * 4 + 1][kk];
      float a2 = sA[tr * 4 + 2][kk], a3 = sA[tr * 4 + 3][kk];
      float4 w4 = *(const float4*)&sW[kk][tc * 4];
      acc[0][0] = fmaf(a0, w4.x, acc[0][0]); acc[0][1] = fmaf(a0, w4.y, acc[0][1]);
      acc[0][2] = fmaf(a0, w4.z, acc[0][2]); acc[0][3] = fmaf(a0, w4.w, acc[0][3]);
      acc[1][0] = fmaf(a1, w4.x, acc[1][0]); acc[1][1] = fmaf(a1, w4.y, acc[1][1]);
      acc[1][2] = fmaf(a1, w4.z, acc[1][2]); acc[1][3] = fmaf(a1, w4.w, acc[1][3]);
      acc[2][0] = fmaf(a2, w4.x, acc[2][0]); acc[2][1] = fmaf(a2, w4.y, acc[2][1]);
      acc[2][2] = fmaf(a2, w4.z, acc[2][2]); acc[2][3] = fmaf(a2, w4.w, acc[2][3]);
      acc[3][0] = fmaf(a3, w4.x, acc[3][0]); acc[3][1] = fmaf(a3, w4.y, acc[3][1]);
      acc[3][2] = fmaf(a3, w4.z, acc[3][2]); acc[3][3] = fmaf(a3, w4.w, acc[3][3]);
    }
  }
#pragma unroll
  for (int i = 0; i < 4; i++) {
    int r = row0 + tr * 4 + i;
#pragma unroll
    for (int j = 0; j < 4; j++) {
      int c = col0 + tc * 4 + j;
      float v = acc[i][j] + bias[c];
      if (ACT == 1) v = fmaxf(v, 0.0f);
      C[(size_t)r * N + c] = v;
    }
  }
}

// ---------- GATv2 edge scores + segment max (one wave per edge) ----------
__global__ void k_edge_score(const float* __restrict__ xl, const float* __restrict__ xr,
                             const float* __restrict__ att, const int* __restrict__ ei,
                             float* __restrict__ score, unsigned* __restrict__ m_enc) {
  __shared__ float sAtt[512];
  const int t = threadIdx.x;
  for (int i = t; i < 512; i += 256) sAtt[i] = att[i];
  __syncthreads();
  const int wv = t >> 6, l = t & 63;
  const int e = blockIdx.x * 4 + wv;
  if (e >= N_EDGE_TOT) return;
  const int s = e_src(ei, e), d = e_dst(ei, e);
  const float* xls = xl + (size_t)s * 512;
  const float* xrd = xr + (size_t)d * 512;
  float ps[8];
#pragma unroll
  for (int h = 0; h < 8; h++) {
    float v = xls[h * 64 + l] + xrd[h * 64 + l];
    v = v > 0.0f ? v : 0.2f * v;  // leaky_relu(0.2)
    ps[h] = v * sAtt[h * 64 + l];
  }
#pragma unroll
  for (int off = 1; off < 64; off <<= 1)
#pragma unroll
    for (int h = 0; h < 8; h++) ps[h] += __shfl_xor(ps[h], off);
  if (l == 0) {
    size_t base = (size_t)e * 8;
#pragma unroll
    for (int h = 0; h < 8; h++) {
      score[base + h] = ps[h];
      atomicMax(&m_enc[d * 8 + h], fenc(ps[h]));
    }
  }
}

// ---------- p = exp(score - m[dst]); denom = segment_sum ----------
__global__ void k_edge_p(const float* __restrict__ score, const unsigned* __restrict__ m_enc,
                         const int* __restrict__ ei, float* __restrict__ p,
                         float* __restrict__ denom) {
  int idx = blockIdx.x * 256 + threadIdx.x;
  if (idx >= N_EDGE_TOT * 8) return;
  int e = idx >> 3, h = idx & 7;
  int d = e_dst(ei, e);
  float m = fdec(m_enc[d * 8 + h]);
  float pv = expf(score[idx] - m);
  p[idx] = pv;
  atomicAdd(&denom[d * 8 + h], pv);
}

// ---------- out[n] = sum_e alpha * xl[src] + bias (CSR, no atomics) ----------
template <int ACT>
__global__ __launch_bounds__(256) void k_aggregate(
    const float* __restrict__ xl, const float* __restrict__ p, const float* __restrict__ denom,
    const int* __restrict__ row_ptr, const int* __restrict__ edge_list,
    const int* __restrict__ ei, const float* __restrict__ bias, float* __restrict__ out) {
  __shared__ float sInv[8];
  const int n = blockIdx.x, t = threadIdx.x;
  if (t < 8) sInv[t] = 1.0f / denom[n * 8 + t];
  __syncthreads();
  const int f0 = t, f1 = t + 256;
  const int h0 = f0 >> 6, h1 = f1 >> 6;
  float acc0 = 0.0f, acc1 = 0.0f;
  const int beg = row_ptr[n], end = row_ptr[n + 1];
  for (int i = beg; i < end; i++) {
    const int e = edge_list[i];
    const int s = e_src(ei, e);
    const float* xs = xl + (size_t)s * 512;
    const float a0 = p[(size_t)e * 8 + h0] * sInv[h0];
    const float a1 = p[(size_t)e * 8 + h1] * sInv[h1];
    acc0 = fmaf(a0, xs[f0], acc0);
    acc1 = fmaf(a1, xs[f1], acc1);
  }
  float v0 = acc0 + bias[f0], v1 = acc1 + bias[f1];
  if (ACT == 1) { v0 = fmaxf(v0, 0.0f); v1 = fmaxf(v1, 0.0f); }
  out[(size_t)n * 512 + f0] = v0;
  out[(size_t)n * 512 + f1] = v1;
}

// ---------- logits + BCE loss + per-graph argmax hits ----------
__global__ __launch_bounds__(1024) void k_final(const float* __restrict__ hc2,
                                                const float* __restrict__ w3,
                                                const float* __restrict__ b3,
                                                const float* __restrict__ y,
                                                float* __restrict__ out) {
  __shared__ float sL[2048];
  __shared__ float sRed[1024];
  __shared__ float sW[64];
  const int t = threadIdx.x;
  if (t < 64) sW[t] = w3[t];
  __syncthreads();
  float lp = 0.0f;
  for (int n = t; n < 2048; n += 1024) {
    const float4* r = (const float4*)(hc2 + (size_t)n * 64);
    float a = 0.0f;
#pragma unroll
    for (int k = 0; k < 16; k++) {
      float4 v = r[k];
      a += v.x * sW[4 * k] + v.y * sW[4 * k + 1] + v.z * sW[4 * k + 2] + v.w * sW[4 * k + 3];
    }
    a += b3[0];
    sL[n] = a;
    lp += fmaxf(a, 0.0f) - a * y[n] + log1pf(expf(-fabsf(a)));
  }
  sRed[t] = lp;
  __syncthreads();
  for (int off = 512; off > 0; off >>= 1) {
    if (t < off) sRed[t] += sRed[t + off];
    __syncthreads();
  }
  if (t == 0) out[0] = sRed[0] * (1.0f / 2048.0f);
  __syncthreads();
  float hit = 0.0f;
  if (t < 64) {
    const int base = t * NPG;
    float bl = sL[base]; int bi = 0;
    float by = y[base];  int byi = 0;
    for (int i = 1; i < NPG - 1; i++) {  // [:, :-1] -> 31 entries, first-max tie rule
      float v = sL[base + i];
      if (v > bl) { bl = v; bi = i; }
      float w = y[base + i];
      if (w > by) { by = w; byi = i; }
    }
    hit = (bi == byi) ? 1.0f : 0.0f;
  }
  __syncthreads();
  sRed[t] = hit;
  __syncthreads();
  for (int off = 512; off > 0; off >>= 1) {
    if (t < off) sRed[t] += sRed[t + off];
    __syncthreads();
  }
  if (t == 0) out[1] = sRed[0] * (1.0f / 64.0f);
}

// ---------- workspace layout (float units) ----------
constexpr size_t OFF_XCAT = 0;                                  // [2048,1024]
constexpr size_t OFF_X1   = OFF_XCAT + (size_t)2048 * 1024;     // [2048,512]
constexpr size_t OFF_XL   = OFF_X1 + (size_t)2048 * 512;
constexpr size_t OFF_XR   = OFF_XL + (size_t)2048 * 512;
constexpr size_t OFF_G1   = OFF_XR + (size_t)2048 * 512;
constexpr size_t OFF_G2   = OFF_G1 + (size_t)2048 * 512;
constexpr size_t OFF_HC1  = OFF_G2 + (size_t)2048 * 512;        // [2048,64]
constexpr size_t OFF_HC2  = OFF_HC1 + (size_t)2048 * 64;
constexpr size_t OFF_SC   = OFF_HC2 + (size_t)2048 * 64;        // [34816,8]
constexpr size_t OFF_P    = OFF_SC + (size_t)N_EDGE_TOT * 8;
constexpr size_t OFF_M    = OFF_P + (size_t)N_EDGE_TOT * 8;     // u32 [2048,8]
constexpr size_t OFF_DEN  = OFF_M + (size_t)2048 * 8;
constexpr size_t OFF_RP   = OFF_DEN + (size_t)2048 * 8;         // int [2052]
constexpr size_t OFF_CNT  = OFF_RP + 2052;                      // int [2048]
constexpr size_t OFF_EL   = OFF_CNT + 2048;                     // int [34816]
constexpr size_t OFF_USH  = OFF_EL + 34816;                     // ushort regions (16B aligned)

// ushort sub-offsets (units: ushorts, from OFF_USH)
constexpr size_t U_W2H = 0,       U_W2L = 4096;
constexpr size_t U_W3H = 8192,    U_W3L = 12288;
constexpr size_t U_W4H = 16384,   U_W4L = 24576;
constexpr size_t U_W5H = 32768,   U_W5L = 98304;   // end 163840
constexpr size_t U_MFH = 163840,  U_MFL = 688128;  // 1024x512, end 1212416
constexpr size_t U_G1LH = 1212416, U_G1LL = 1474560;
constexpr size_t U_G1RH = 1736704, U_G1RL = 1998848;
constexpr size_t U_G2LH = 2260992, U_G2LL = 2523136;
constexpr size_t U_G2RH = 2785280, U_G2RL = 3047424;  // end 3309568
constexpr size_t U_CL1H = 3309568, U_CL1L = 3342336;  // end 3375104
constexpr size_t U_END  = 3375104;
constexpr size_t WS_NEED_FULL = (OFF_USH + (U_END + 1) / 2) * sizeof(float);
constexpr size_t WS_NEED_MIN  = (OFF_USH + (163840 + 1) / 2) * sizeof(float);

extern "C" void kernel_launch(void* const* d_in, const int* in_sizes, int n_in,
                              void* d_out, int out_size, void* d_ws, size_t ws_size,
                              hipStream_t stream) {
  const float* pcd   = (const float*)d_in[0];
  const float* vol   = (const float*)d_in[1];
  const float* dist  = (const float*)d_in[2];
  const float* ecnt  = (const float*)d_in[3];
  const float* y     = (const float*)d_in[4];
  const float* pn_w1 = (const float*)d_in[5];
  const float* pn_w2 = (const float*)d_in[6];
  const float* pn_w3 = (const float*)d_in[7];
  const float* pn_w4 = (const float*)d_in[8];
  const float* pn_w5 = (const float*)d_in[9];
  const float* mf_w1 = (const float*)d_in[10];
  const float* mf_b1 = (const float*)d_in[11];
  const float* mf_w2 = (const float*)d_in[12];
  const float* mf_b2 = (const float*)d_in[13];
  const float* g1_wl = (const float*)d_in[14];
  const float* g1_bl = (const float*)d_in[15];
  const float* g1_wr = (const float*)d_in[16];
  const float* g1_br = (const float*)d_in[17];
  const float* g1_at = (const float*)d_in[18];
  const float* g1_bi = (const float*)d_in[19];
  const float* g2_wl = (const float*)d_in[20];
  const float* g2_bl = (const float*)d_in[21];
  const float* g2_wr = (const float*)d_in[22];
  const float* g2_br = (const float*)d_in[23];
  const float* g2_at = (const float*)d_in[24];
  const float* g2_bi = (const float*)d_in[25];
  const float* cl_w1 = (const float*)d_in[26];
  const float* cl_b1 = (const float*)d_in[27];
  const float* cl_w2 = (const float*)d_in[28];
  const float* cl_b2 = (const float*)d_in[29];
  const float* cl_w3 = (const float*)d_in[30];
  const float* cl_b3 = (const float*)d_in[31];
  const int*   ei    = (const int*)d_in[32];
  float* out = (float*)d_out;
  float* ws  = (float*)d_ws;

  float* xcat = ws + OFF_XCAT;
  float* x1   = ws + OFF_X1;
  float* xlb  = ws + OFF_XL;
  float* xrb  = ws + OFF_XR;
  float* g1o  = ws + OFF_G1;
  float* g2o  = ws + OFF_G2;
  float* hc1  = ws + OFF_HC1;
  float* hc2  = ws + OFF_HC2;
  float* sc   = ws + OFF_SC;
  float* pbuf = ws + OFF_P;
  unsigned* menc = (unsigned*)(ws + OFF_M);
  float* den  = ws + OFF_DEN;
  int* rp     = (int*)(ws + OFF_RP);
  int* cnt    = (int*)(ws + OFF_CNT);
  int* el     = (int*)(ws + OFF_EL);
  ushort_t* ush = (ushort_t*)(ws + OFF_USH);

  const bool full = (ws_size >= WS_NEED_FULL);

  // --- build CSR by dst (shared by both GAT layers) ---
  hipMemsetAsync(cnt, 0, 2048 * sizeof(int), stream);
  k_hist<<<(N_EDGE_TOT + 255) / 256, 256, 0, stream>>>(ei, cnt);
  k_scan<<<1, 256, 0, stream>>>(cnt, rp);
  hipMemsetAsync(cnt, 0, 2048 * sizeof(int), stream);
  k_scatter<<<(N_EDGE_TOT + 255) / 256, 256, 0, stream>>>(ei, rp, cnt, el);

  // --- weight prep ---
  k_split<<<16, 256, 0, stream>>>(pn_w2, ush + U_W2H, ush + U_W2L, 64, 64);
  k_split<<<16, 256, 0, stream>>>(pn_w3, ush + U_W3H, ush + U_W3L, 64, 64);
  k_split<<<32, 256, 0, stream>>>(pn_w4, ush + U_W4H, ush + U_W4L, 64, 128);
  k_split<<<256, 256, 0, stream>>>(pn_w5, ush + U_W5H, ush + U_W5L, 128, 512);
  if (full) {
    k_split<<<2048, 256, 0, stream>>>(mf_w2, ush + U_MFH, ush + U_MFL, 1024, 512);
    k_split<<<1024, 256, 0, stream>>>(g1_wl, ush + U_G1LH, ush + U_G1LL, 512, 512);
    k_split<<<1024, 256, 0, stream>>>(g1_wr, ush + U_G1RH, ush + U_G1RL, 512, 512);
    k_split<<<1024, 256, 0, stream>>>(g2_wl, ush + U_G2LH, ush + U_G2LL, 512, 512);
    k_split<<<1024, 256, 0, stream>>>(g2_wr, ush + U_G2RH, ush + U_G2RL, 512, 512);
    k_split<<<128, 256, 0, stream>>>(cl_w1, ush + U_CL1H, ush + U_CL1L, 512, 64);
  }

  // --- PointNet + multi-feature ---
  k_pointnet<<<N_NODES, 512, 0, stream>>>(pcd, pn_w1,
      ush + U_W2H, ush + U_W2L, ush + U_W3H, ush + U_W3L,
      ush + U_W4H, ush + U_W4L, ush + U_W5H, ush + U_W5L, xcat);
  k_vdf<<<2048 * 512 / 256, 256, 0, stream>>>(vol, dist, ecnt, mf_w1, mf_b1, xcat);
  if (full)
    k_mgemm<1><<<dim3(32, 8), 256, 0, stream>>>(xcat, ush + U_MFH, ush + U_MFL, mf_b2, x1, 2048, 512, 1024);
  else
    k_gemm<1><<<dim3(32, 8), 256, 0, stream>>>(xcat, mf_w2, mf_b2, x1, 2048, 512, 1024);

  // --- GAT layer 1 ---
  if (full) {
    k_mgemm<0><<<dim3(32, 8), 256, 0, stream>>>(x1, ush + U_G1LH, ush + U_G1LL, g1_bl, xlb, 2048, 512, 512);
    k_mgemm<0><<<dim3(32, 8), 256, 0, stream>>>(x1, ush + U_G1RH, ush + U_G1RL, g1_br, xrb, 2048, 512, 512);
  } else {
    k_gemm<0><<<dim3(32, 8), 256, 0, stream>>>(x1, g1_wl, g1_bl, xlb, 2048, 512, 512);
    k_gemm<0><<<dim3(32, 8), 256, 0, stream>>>(x1, g1_wr, g1_br, xrb, 2048, 512, 512);
  }
  hipMemsetAsync(menc, 0, 2048 * 8 * sizeof(unsigned), stream);
  hipMemsetAsync(den, 0, 2048 * 8 * sizeof(float), stream);
  k_edge_score<<<N_EDGE_TOT / 4, 256, 0, stream>>>(xlb, xrb, g1_at, ei, sc, menc);
  k_edge_p<<<N_EDGE_TOT * 8 / 256, 256, 0, stream>>>(sc, menc, ei, pbuf, den);
  k_aggregate<1><<<N_NODES, 256, 0, stream>>>(xlb, pbuf, den, rp, el, ei, g1_bi, g1o);

  // --- GAT layer 2 ---
  if (full) {
    k_mgemm<0><<<dim3(32, 8), 256, 0, stream>>>(g1o, ush + U_G2LH, ush + U_G2LL, g2_bl, xlb, 2048, 512, 512);
    k_mgemm<0><<<dim3(32, 8), 256, 0, stream>>>(g1o, ush + U_G2RH, ush + U_G2RL, g2_br, xrb, 2048, 512, 512);
  } else {
    k_gemm<0><<<dim3(32, 8), 256, 0, stream>>>(g1o, g2_wl, g2_bl, xlb, 2048, 512, 512);
    k_gemm<0><<<dim3(32, 8), 256, 0, stream>>>(g1o, g2_wr, g2_br, xrb, 2048, 512, 512);
  }
  hipMemsetAsync(menc, 0, 2048 * 8 * sizeof(unsigned), stream);
  hipMemsetAsync(den, 0, 2048 * 8 * sizeof(float), stream);
  k_edge_score<<<N_EDGE_TOT / 4, 256, 0, stream>>>(xlb, xrb, g2_at, ei, sc, menc);
  k_edge_p<<<N_EDGE_TOT * 8 / 256, 256, 0, stream>>>(sc, menc, ei, pbuf, den);
  k_aggregate<0><<<N_NODES, 256, 0, stream>>>(xlb, pbuf, den, rp, el, ei, g2_bi, g2o);

  // --- classifier + loss/acc ---
  if (full)
    k_mgemm<1><<<dim3(32, 1), 256, 0, stream>>>(g2o, ush + U_CL1H, ush + U_CL1L, cl_b1, hc1, 2048, 64, 512);
  else
    k_gemm<1><<<dim3(32, 1), 256, 0, stream>>>(g2o, cl_w1, cl_b1, hc1, 2048, 64, 512);
  k_gemm<1><<<dim3(32, 1), 256, 0, stream>>>(hc1, cl_w2, cl_b2, hc2, 2048, 64, 64);
  k_final<<<1, 1024, 0, stream>>>(hc2, cl_w3, cl_b3, y, out);
}